// Round 1
// baseline (1135.677 us; speedup 1.0000x reference)
//
#include <hip/hip_runtime.h>

// ---------------------------------------------------------------------------
// GraphSAGE (mean) x3 layers: h' = mean_agg(h)@Wl + h@Wr + b, relu between.
// Strategy: build CSR (by dst) once, then per layer: aggregate + fused GEMM.
// GEMM is fp32 vector (no fp32 MFMA on CDNA4), 64x256 full-row-stripe tiles
// so it can run in place on d_out.
// ---------------------------------------------------------------------------

__global__ void count_deg_kernel(const int* __restrict__ dst,
                                 int* __restrict__ deg, int E) {
    int e = blockIdx.x * blockDim.x + threadIdx.x;
    if (e < E) atomicAdd(&deg[dst[e]], 1);
}

// Single-block chunked Hillis-Steele scan: deg -> exclusive rowptr, cursor,
// and inv_deg = 1/max(deg,1).
__global__ void scan_kernel(const int* __restrict__ deg,
                            int* __restrict__ rowptr,
                            int* __restrict__ cursor,
                            float* __restrict__ inv_deg, int n) {
    __shared__ int s[1024];
    __shared__ int s_carry;
    if (threadIdx.x == 0) s_carry = 0;
    __syncthreads();
    for (int base = 0; base < n; base += 1024) {
        int i = base + (int)threadIdx.x;
        int v = (i < n) ? deg[i] : 0;
        s[threadIdx.x] = v;
        __syncthreads();
        for (int off = 1; off < 1024; off <<= 1) {
            int t = ((int)threadIdx.x >= off) ? s[threadIdx.x - off] : 0;
            __syncthreads();
            s[threadIdx.x] += t;
            __syncthreads();
        }
        int carry = s_carry;
        if (i < n) {
            int excl = carry + s[threadIdx.x] - v;
            rowptr[i] = excl;
            cursor[i] = excl;
            inv_deg[i] = 1.0f / (float)max(v, 1);
        }
        __syncthreads();
        if (threadIdx.x == 1023) s_carry = carry + s[1023];
        __syncthreads();
    }
    if (threadIdx.x == 0) rowptr[n] = s_carry;
}

__global__ void fill_csr_kernel(const int* __restrict__ src,
                                const int* __restrict__ dst,
                                int* __restrict__ cursor,
                                int* __restrict__ csr_src, int E) {
    int e = blockIdx.x * blockDim.x + threadIdx.x;
    if (e < E) {
        int d = dst[e];
        int pos = atomicAdd(&cursor[d], 1);
        csr_src[pos] = src[e];
    }
}

// One wave per destination node; lane handles a float4 of the 256-dim row.
__global__ void aggregate_kernel(const float* __restrict__ h,
                                 const int* __restrict__ rowptr,
                                 const int* __restrict__ csr_src,
                                 const float* __restrict__ inv_deg,
                                 float* __restrict__ agg, int n) {
    int wave = threadIdx.x >> 6;
    int lane = threadIdx.x & 63;
    int v = blockIdx.x * 4 + wave;
    if (v >= n) return;
    int beg = rowptr[v], end = rowptr[v + 1];
    const float4* h4 = (const float4*)h;
    float4 acc = make_float4(0.f, 0.f, 0.f, 0.f);
    for (int e = beg; e < end; ++e) {
        int u = csr_src[e];
        float4 t = h4[(size_t)u * 64 + lane];
        acc.x += t.x; acc.y += t.y; acc.z += t.z; acc.w += t.w;
    }
    float sc = inv_deg[v];
    float4 o = make_float4(acc.x * sc, acc.y * sc, acc.z * sc, acc.w * sc);
    ((float4*)agg)[(size_t)v * 64 + lane] = o;
}

// C[r0:r0+64][0:256] = agg@Wl + h@Wr + b  (in place on h; full row stripe so
// no cross-block read/write hazard). 256 threads, 4x16 micro-tile per thread.
// LDS: As transposed [16][68] (pad), Ws groups on 20-float pitch (bank-free).
__global__ __launch_bounds__(256, 2) void sage_gemm_kernel(
    const float* __restrict__ agg, float* __restrict__ h,
    const float* __restrict__ Wl, const float* __restrict__ Wr,
    const float* __restrict__ bias, int M, int do_relu) {
    __shared__ float As[16][68];
    __shared__ float Ws[16][320];

    const int tid = threadIdx.x;
    const int rg = tid >> 4;       // 0..15 -> rows rg*4..+3
    const int cg = tid & 15;       // 0..15 -> cols cg*16..+15
    const int r0 = blockIdx.x * 64;

    float acc[4][16];
#pragma unroll
    for (int i = 0; i < 4; ++i)
#pragma unroll
        for (int j = 0; j < 16; ++j) acc[i][j] = 0.0f;

    const int ar = tid >> 2;           // A staging: row 0..63
    const int ak = (tid & 3) << 2;     // A staging: k offset 0,4,8,12
    const int wr = (tid >> 6) << 2;    // W staging: base row 0,4,8,12
    const int wc = (tid & 63) << 2;    // W staging: col 0..252
    const int wg = wc >> 4;            // group
    const int wo = wc & 15;            // offset in group

#pragma unroll
    for (int s = 0; s < 2; ++s) {
        const float* A = s ? h : agg;
        const float* W = s ? Wr : Wl;
        for (int k0 = 0; k0 < 256; k0 += 16) {
            // stage A tile (transposed into LDS)
            float4 av = make_float4(0.f, 0.f, 0.f, 0.f);
            if (r0 + ar < M)
                av = *(const float4*)&A[(size_t)(r0 + ar) * 256 + k0 + ak];
            As[ak + 0][ar] = av.x;
            As[ak + 1][ar] = av.y;
            As[ak + 2][ar] = av.z;
            As[ak + 3][ar] = av.w;
            // stage W tile (group-padded layout)
#pragma unroll
            for (int i = 0; i < 4; ++i) {
                float4 wv = *(const float4*)&W[(size_t)(k0 + wr + i) * 256 + wc];
                *(float4*)&Ws[wr + i][wg * 20 + wo] = wv;
            }
            __syncthreads();
#pragma unroll
            for (int kk = 0; kk < 16; ++kk) {
                float4 a4 = *(const float4*)&As[kk][rg << 2];
                float4 w0 = *(const float4*)&Ws[kk][cg * 20 + 0];
                float4 w1 = *(const float4*)&Ws[kk][cg * 20 + 4];
                float4 w2 = *(const float4*)&Ws[kk][cg * 20 + 8];
                float4 w3 = *(const float4*)&Ws[kk][cg * 20 + 12];
                float a[4] = {a4.x, a4.y, a4.z, a4.w};
                float w[16] = {w0.x, w0.y, w0.z, w0.w, w1.x, w1.y, w1.z, w1.w,
                               w2.x, w2.y, w2.z, w2.w, w3.x, w3.y, w3.z, w3.w};
#pragma unroll
                for (int i = 0; i < 4; ++i)
#pragma unroll
                    for (int j = 0; j < 16; ++j) acc[i][j] += a[i] * w[j];
            }
            __syncthreads();
        }
    }

    // epilogue: bias (+relu), write full stripe back in place
    float bv[16];
#pragma unroll
    for (int j = 0; j < 16; ++j) bv[j] = bias[cg * 16 + j];
#pragma unroll
    for (int i = 0; i < 4; ++i) {
        int row = r0 + (rg << 2) + i;
        if (row < M) {
#pragma unroll
            for (int j4 = 0; j4 < 4; ++j4) {
                float4 o;
                o.x = acc[i][j4 * 4 + 0] + bv[j4 * 4 + 0];
                o.y = acc[i][j4 * 4 + 1] + bv[j4 * 4 + 1];
                o.z = acc[i][j4 * 4 + 2] + bv[j4 * 4 + 2];
                o.w = acc[i][j4 * 4 + 3] + bv[j4 * 4 + 3];
                if (do_relu) {
                    o.x = fmaxf(o.x, 0.f);
                    o.y = fmaxf(o.y, 0.f);
                    o.z = fmaxf(o.z, 0.f);
                    o.w = fmaxf(o.w, 0.f);
                }
                *(float4*)&h[(size_t)row * 256 + cg * 16 + j4 * 4] = o;
            }
        }
    }
}

extern "C" void kernel_launch(void* const* d_in, const int* in_sizes, int n_in,
                              void* d_out, int out_size, void* d_ws, size_t ws_size,
                              hipStream_t stream) {
    const int D = 256;
    const int N = in_sizes[0] / D;
    const int E = in_sizes[1] / 2;
    const int L = in_sizes[2] / (D * D);

    const float* x  = (const float*)d_in[0];
    const int*   ei = (const int*)d_in[1];
    const float* Wl = (const float*)d_in[2];
    const float* Wr = (const float*)d_in[3];
    const float* b  = (const float*)d_in[4];
    const int* src = ei;
    const int* dst = ei + E;

    // workspace layout (256B aligned slots)
    size_t off = 0;
    auto alloc = [&](size_t bytes) {
        void* p = (char*)d_ws + off;
        off += (bytes + 255) & ~(size_t)255;
        return p;
    };
    int*   deg     = (int*)alloc((size_t)N * 4);
    int*   rowptr  = (int*)alloc((size_t)(N + 1) * 4);
    int*   cursor  = (int*)alloc((size_t)N * 4);
    float* inv_deg = (float*)alloc((size_t)N * 4);
    int*   csr_src = (int*)alloc((size_t)E * 4);
    float* agg     = (float*)alloc((size_t)N * D * 4);
    (void)ws_size;

    float* h = (float*)d_out;

    // CSR build
    hipMemsetAsync(deg, 0, (size_t)N * 4, stream);
    hipLaunchKernelGGL(count_deg_kernel, dim3((E + 255) / 256), dim3(256), 0,
                       stream, dst, deg, E);
    hipLaunchKernelGGL(scan_kernel, dim3(1), dim3(1024), 0, stream,
                       deg, rowptr, cursor, inv_deg, N);
    hipLaunchKernelGGL(fill_csr_kernel, dim3((E + 255) / 256), dim3(256), 0,
                       stream, src, dst, cursor, csr_src, E);

    // h <- x
    hipMemcpyAsync(h, x, (size_t)N * D * sizeof(float),
                   hipMemcpyDeviceToDevice, stream);

    for (int l = 0; l < L; ++l) {
        hipLaunchKernelGGL(aggregate_kernel, dim3((N + 3) / 4), dim3(256), 0,
                           stream, h, rowptr, csr_src, inv_deg, agg, N);
        hipLaunchKernelGGL(sage_gemm_kernel, dim3((N + 63) / 64), dim3(256), 0,
                           stream, agg, h,
                           Wl + (size_t)l * D * D, Wr + (size_t)l * D * D,
                           b + (size_t)l * D, N, (l < L - 1) ? 1 : 0);
    }
}

// Round 2
// 649.031 us; speedup vs baseline: 1.7498x; 1.7498x over previous
//
#include <hip/hip_runtime.h>

// ---------------------------------------------------------------------------
// GraphSAGE (mean) x3: h' = mean_agg(h)@Wl + h@Wr + b, relu between layers.
// R2: GEMM -> bf16 MFMA (16x16x32) with 3-term hi/lo split (fp32-accurate);
//     aggregation gathers a bf16 shadow of h (halved gather bytes).
// ---------------------------------------------------------------------------

typedef __attribute__((ext_vector_type(8))) short bf16x8;
typedef __attribute__((ext_vector_type(4))) float f32x4;

__device__ __forceinline__ unsigned short f2bf_rne(float f) {
    unsigned u = __float_as_uint(f);
    unsigned r = u + 0x7fffu + ((u >> 16) & 1u);
    return (unsigned short)(r >> 16);
}
__device__ __forceinline__ void split_bf(float f, unsigned short& hi,
                                         unsigned short& lo) {
    hi = f2bf_rne(f);
    float fh = __uint_as_float(((unsigned)hi) << 16);
    lo = f2bf_rne(f - fh);
}

// ------------------------------- CSR build --------------------------------
__global__ void count_deg_kernel(const int* __restrict__ dst,
                                 int* __restrict__ deg, int E) {
    int e = blockIdx.x * blockDim.x + threadIdx.x;
    if (e < E) atomicAdd(&deg[dst[e]], 1);
}

__global__ void scan_kernel(const int* __restrict__ deg,
                            int* __restrict__ rowptr,
                            int* __restrict__ cursor,
                            float* __restrict__ inv_deg, int n) {
    __shared__ int s[1024];
    __shared__ int s_carry;
    if (threadIdx.x == 0) s_carry = 0;
    __syncthreads();
    for (int base = 0; base < n; base += 1024) {
        int i = base + (int)threadIdx.x;
        int v = (i < n) ? deg[i] : 0;
        s[threadIdx.x] = v;
        __syncthreads();
        for (int off = 1; off < 1024; off <<= 1) {
            int t = ((int)threadIdx.x >= off) ? s[threadIdx.x - off] : 0;
            __syncthreads();
            s[threadIdx.x] += t;
            __syncthreads();
        }
        int carry = s_carry;
        if (i < n) {
            int excl = carry + s[threadIdx.x] - v;
            rowptr[i] = excl;
            cursor[i] = excl;
            inv_deg[i] = 1.0f / (float)max(v, 1);
        }
        __syncthreads();
        if (threadIdx.x == 1023) s_carry = carry + s[1023];
        __syncthreads();
    }
    if (threadIdx.x == 0) rowptr[n] = s_carry;
}

__global__ void fill_csr_kernel(const int* __restrict__ src,
                                const int* __restrict__ dst,
                                int* __restrict__ cursor,
                                int* __restrict__ csr_src, int E) {
    int e = blockIdx.x * blockDim.x + threadIdx.x;
    if (e < E) {
        int d = dst[e];
        int pos = atomicAdd(&cursor[d], 1);
        csr_src[pos] = src[e];
    }
}

// --------------------------- bf16 conversions -----------------------------
__global__ void x_to_bf16_kernel(const float* __restrict__ x,
                                 unsigned short* __restrict__ h16, int n4) {
    int i = blockIdx.x * blockDim.x + threadIdx.x;
    if (i >= n4) return;
    float4 v = ((const float4*)x)[i];
    unsigned a = (unsigned)f2bf_rne(v.x) | ((unsigned)f2bf_rne(v.y) << 16);
    unsigned b = (unsigned)f2bf_rne(v.z) | ((unsigned)f2bf_rne(v.w) << 16);
    ((uint2*)h16)[i] = make_uint2(a, b);
}

// Pre-split W into fragment-ordered bf16 hi/lo:
// per (layer,source): [step(8)][tile(16)][g(4)][col(16)][j(8)]
__global__ void presplit_w_kernel(const float* __restrict__ Wl,
                                  const float* __restrict__ Wr,
                                  unsigned short* __restrict__ Wf_hi,
                                  unsigned short* __restrict__ Wf_lo,
                                  int total) {
    int idx = blockIdx.x * blockDim.x + threadIdx.x;
    if (idx >= total) return;
    int l = idx >> 17;
    int rem = idx & 131071;
    int s = rem >> 16;
    int kc = rem & 65535;
    int k = kc >> 8, c = kc & 255;
    const float* W = s ? Wr : Wl;
    float w = W[((size_t)l * 256 + k) * 256 + c];
    unsigned short hi, lo;
    split_bf(w, hi, lo);
    int step = k >> 5, g = (k >> 3) & 3, j = k & 7;
    int tile = c >> 4, col = c & 15;
    int fi = ((l * 2 + s) << 16) +
             ((((step * 16 + tile) * 4 + g) * 16 + col) * 8 + j);
    Wf_hi[fi] = hi;
    Wf_lo[fi] = lo;
}

// ------------------------------ aggregation -------------------------------
// One wave per dst node; gathers bf16 rows (512B/row), fp32 accumulate.
__global__ void aggregate_kernel(const unsigned short* __restrict__ h16,
                                 const int* __restrict__ rowptr,
                                 const int* __restrict__ csr_src,
                                 const float* __restrict__ inv_deg,
                                 float* __restrict__ agg, int n) {
    int wave = threadIdx.x >> 6;
    int lane = threadIdx.x & 63;
    int v = blockIdx.x * 4 + wave;
    if (v >= n) return;
    int beg = rowptr[v], end = rowptr[v + 1];
    const uint2* h2 = (const uint2*)h16;
    float a0 = 0.f, a1 = 0.f, a2 = 0.f, a3 = 0.f;
    for (int e = beg; e < end; ++e) {
        int u = csr_src[e];
        uint2 t = h2[(size_t)u * 64 + lane];
        a0 += __uint_as_float(t.x << 16);
        a1 += __uint_as_float(t.x & 0xffff0000u);
        a2 += __uint_as_float(t.y << 16);
        a3 += __uint_as_float(t.y & 0xffff0000u);
    }
    float sc = inv_deg[v];
    ((float4*)agg)[(size_t)v * 64 + lane] =
        make_float4(a0 * sc, a1 * sc, a2 * sc, a3 * sc);
}

// ------------------------------- MFMA GEMM --------------------------------
// C[r0:r0+128][0:256] = agg@Wl + h@Wr + b (in place on h; full row stripe).
// 4 waves; wave w owns rows [w*32,w*32+32) x all 256 cols = 2x16 tiles of
// 16x16. 3-term bf16 split per operand pair. flags: 1=relu, 2=write shadow.
__global__ __launch_bounds__(256, 2) void sage_gemm_mfma(
    const float* __restrict__ agg, float* __restrict__ h,
    unsigned short* __restrict__ h16,
    const unsigned short* __restrict__ Wf_hi,
    const unsigned short* __restrict__ Wf_lo,
    const float* __restrict__ bias, int M, int flags) {
    __shared__ __align__(16) unsigned short Ah[2][4][128][8];   // 16 KB
    __shared__ __align__(16) unsigned short Ws[2][16][4][16][8]; // 32 KB

    const int tid = threadIdx.x;
    const int wave = tid >> 6, lane = tid & 63;
    const int l15 = lane & 15, lg = lane >> 4;
    const int r0 = blockIdx.x * 128;

    f32x4 acc[2][16];
#pragma unroll
    for (int rt = 0; rt < 2; ++rt)
#pragma unroll
        for (int t = 0; t < 16; ++t) acc[rt][t] = (f32x4)(0.0f);

    const int s_row = tid >> 1;      // staging row 0..127
    const int s_kh = tid & 1;        // staging k-half (16 k's)

#pragma unroll
    for (int s = 0; s < 2; ++s) {
        const float* A = s ? h : agg;
        const unsigned short* Whg = Wf_hi + s * 65536;
        const unsigned short* Wlg = Wf_lo + s * 65536;
        for (int k0 = 0; k0 < 256; k0 += 32) {
            // ---- stage A tile: fp32 -> hi/lo bf16, fragment order ----
            float vals[16];
            int grow = r0 + s_row;
            if (grow < M) {
                const float4* p =
                    (const float4*)&A[(size_t)grow * 256 + k0 + s_kh * 16];
#pragma unroll
                for (int q = 0; q < 4; ++q) {
                    float4 v = p[q];
                    vals[q * 4 + 0] = v.x;
                    vals[q * 4 + 1] = v.y;
                    vals[q * 4 + 2] = v.z;
                    vals[q * 4 + 3] = v.w;
                }
            } else {
#pragma unroll
                for (int q = 0; q < 16; ++q) vals[q] = 0.0f;
            }
#pragma unroll
            for (int gg = 0; gg < 2; ++gg) {
                bf16x8 hv, lv;
#pragma unroll
                for (int j = 0; j < 8; ++j) {
                    unsigned short hi, lo;
                    split_bf(vals[gg * 8 + j], hi, lo);
                    hv[j] = (short)hi;
                    lv[j] = (short)lo;
                }
                *(bf16x8*)&Ah[0][s_kh * 2 + gg][s_row][0] = hv;
                *(bf16x8*)&Ah[1][s_kh * 2 + gg][s_row][0] = lv;
            }
            // ---- stage W chunk (already fragment-ordered): linear copy ----
            {
                const uint4* gh = (const uint4*)(Whg + (k0 >> 5) * 8192);
                const uint4* gl = (const uint4*)(Wlg + (k0 >> 5) * 8192);
                uint4* lh = (uint4*)&Ws[0][0][0][0][0];
                uint4* ll = (uint4*)&Ws[1][0][0][0][0];
#pragma unroll
                for (int i = 0; i < 4; ++i) {
                    lh[i * 256 + tid] = gh[i * 256 + tid];
                    ll[i * 256 + tid] = gl[i * 256 + tid];
                }
            }
            __syncthreads();
            // ---- compute ----
            bf16x8 ahi[2], alo[2];
#pragma unroll
            for (int rt = 0; rt < 2; ++rt) {
                int row = wave * 32 + rt * 16 + l15;
                ahi[rt] = *(const bf16x8*)&Ah[0][lg][row][0];
                alo[rt] = *(const bf16x8*)&Ah[1][lg][row][0];
            }
#pragma unroll
            for (int t = 0; t < 16; ++t) {
                bf16x8 bhi = *(const bf16x8*)&Ws[0][t][lg][l15][0];
                bf16x8 blo = *(const bf16x8*)&Ws[1][t][lg][l15][0];
#pragma unroll
                for (int rt = 0; rt < 2; ++rt) {
                    acc[rt][t] = __builtin_amdgcn_mfma_f32_16x16x32_bf16(
                        ahi[rt], bhi, acc[rt][t], 0, 0, 0);
                    acc[rt][t] = __builtin_amdgcn_mfma_f32_16x16x32_bf16(
                        alo[rt], bhi, acc[rt][t], 0, 0, 0);
                    acc[rt][t] = __builtin_amdgcn_mfma_f32_16x16x32_bf16(
                        ahi[rt], blo, acc[rt][t], 0, 0, 0);
                }
            }
            __syncthreads();
        }
    }

    // ---- epilogue: bias (+relu), fp32 out + optional bf16 shadow ----
    const int do_relu = flags & 1;
    const int do_shadow = flags & 2;
    float bv[16];
#pragma unroll
    for (int t = 0; t < 16; ++t) bv[t] = bias[t * 16 + l15];
#pragma unroll
    for (int rt = 0; rt < 2; ++rt) {
#pragma unroll
        for (int r = 0; r < 4; ++r) {
            int grow = r0 + wave * 32 + rt * 16 + lg * 4 + r;
            if (grow < M) {
#pragma unroll
                for (int t = 0; t < 16; ++t) {
                    float o = acc[rt][t][r] + bv[t];
                    if (do_relu) o = fmaxf(o, 0.0f);
                    int col = t * 16 + l15;
                    h[(size_t)grow * 256 + col] = o;
                    if (do_shadow)
                        h16[(size_t)grow * 256 + col] = f2bf_rne(o);
                }
            }
        }
    }
}

// --------------------------------- launch ---------------------------------
extern "C" void kernel_launch(void* const* d_in, const int* in_sizes, int n_in,
                              void* d_out, int out_size, void* d_ws, size_t ws_size,
                              hipStream_t stream) {
    const int D = 256;
    const int N = in_sizes[0] / D;
    const int E = in_sizes[1] / 2;
    const int L = in_sizes[2] / (D * D);

    const float* x  = (const float*)d_in[0];
    const int*   ei = (const int*)d_in[1];
    const float* Wl = (const float*)d_in[2];
    const float* Wr = (const float*)d_in[3];
    const float* b  = (const float*)d_in[4];
    const int* src = ei;
    const int* dst = ei + E;

    size_t off = 0;
    auto alloc = [&](size_t bytes) {
        void* p = (char*)d_ws + off;
        off += (bytes + 255) & ~(size_t)255;
        return p;
    };
    int*   deg     = (int*)alloc((size_t)N * 4);
    int*   rowptr  = (int*)alloc((size_t)(N + 1) * 4);
    int*   cursor  = (int*)alloc((size_t)N * 4);
    float* inv_deg = (float*)alloc((size_t)N * 4);
    int*   csr_src = (int*)alloc((size_t)E * 4);
    float* agg     = (float*)alloc((size_t)N * D * 4);
    unsigned short* h16   = (unsigned short*)alloc((size_t)N * D * 2);
    unsigned short* Wf_hi = (unsigned short*)alloc((size_t)L * 2 * 65536 * 2);
    unsigned short* Wf_lo = (unsigned short*)alloc((size_t)L * 2 * 65536 * 2);
    (void)ws_size;

    float* h = (float*)d_out;

    // CSR build
    hipMemsetAsync(deg, 0, (size_t)N * 4, stream);
    hipLaunchKernelGGL(count_deg_kernel, dim3((E + 255) / 256), dim3(256), 0,
                       stream, dst, deg, E);
    hipLaunchKernelGGL(scan_kernel, dim3(1), dim3(1024), 0, stream,
                       deg, rowptr, cursor, inv_deg, N);
    hipLaunchKernelGGL(fill_csr_kernel, dim3((E + 255) / 256), dim3(256), 0,
                       stream, src, dst, cursor, csr_src, E);

    // weight pre-split + x shadow + h <- x
    int wtotal = L * 2 * 65536;
    hipLaunchKernelGGL(presplit_w_kernel, dim3((wtotal + 255) / 256), dim3(256),
                       0, stream, Wl, Wr, Wf_hi, Wf_lo, wtotal);
    hipLaunchKernelGGL(x_to_bf16_kernel, dim3((N * D / 4 + 255) / 256),
                       dim3(256), 0, stream, x, h16, N * D / 4);
    hipMemcpyAsync(h, x, (size_t)N * D * sizeof(float),
                   hipMemcpyDeviceToDevice, stream);

    const int gemm_blocks = (N + 127) / 128;
    for (int l = 0; l < L; ++l) {
        hipLaunchKernelGGL(aggregate_kernel, dim3((N + 3) / 4), dim3(256), 0,
                           stream, h16, rowptr, csr_src, inv_deg, agg, N);
        int flags = (l < L - 1) ? 3 : 0;  // relu + shadow for hidden layers
        hipLaunchKernelGGL(sage_gemm_mfma, dim3(gemm_blocks), dim3(256), 0,
                           stream, agg, h, h16,
                           Wf_hi + (size_t)l * 2 * 65536,
                           Wf_lo + (size_t)l * 2 * 65536,
                           b + (size_t)l * D, N, flags);
    }
}

// Round 3
// 629.916 us; speedup vs baseline: 1.8029x; 1.0303x over previous
//
#include <hip/hip_runtime.h>

// ---------------------------------------------------------------------------
// GraphSAGE (mean) x3: h' = mean_agg(h)@Wl + h@Wr + b, relu between layers.
// R3: multi-block scan; all GEMM operands pre-split into bf16 hi/lo pairs so
// the MFMA hot loop stages with pure copies; agg pair stored in d_out row
// slots (final layer overwrites in place); no fp32 intermediate h at all.
// ---------------------------------------------------------------------------

typedef __attribute__((ext_vector_type(8))) short bf16x8;
typedef __attribute__((ext_vector_type(4))) float f32x4;

__device__ __forceinline__ unsigned short f2bf_rne(float f) {
    unsigned u = __float_as_uint(f);
    unsigned r = u + 0x7fffu + ((u >> 16) & 1u);
    return (unsigned short)(r >> 16);
}
__device__ __forceinline__ void split_bf(float f, unsigned short& hi,
                                         unsigned short& lo) {
    hi = f2bf_rne(f);
    float fh = __uint_as_float(((unsigned)hi) << 16);
    lo = f2bf_rne(f - fh);
}

// ------------------------------- CSR build --------------------------------
__global__ void count_deg_kernel(const int* __restrict__ dst,
                                 int* __restrict__ deg, int E) {
    int e = blockIdx.x * blockDim.x + threadIdx.x;
    if (e < E) atomicAdd(&deg[dst[e]], 1);
}

__device__ __forceinline__ int block_excl_scan_256(int v, int tid) {
    int lane = tid & 63, w = tid >> 6;
    int x = v;
#pragma unroll
    for (int off = 1; off < 64; off <<= 1) {
        int y = __shfl_up(x, off);
        if (lane >= off) x += y;
    }
    __shared__ int wsum[4], woff[4];
    if (lane == 63) wsum[w] = x;
    __syncthreads();
    if (tid == 0) {
        int a = 0;
#pragma unroll
        for (int i = 0; i < 4; ++i) { woff[i] = a; a += wsum[i]; }
    }
    __syncthreads();
    return woff[w] + x - v;
}

// phase 1: per-1024-chunk sums
__global__ void scan_phase1(const int* __restrict__ deg,
                            int* __restrict__ partial, int n) {
    int base = blockIdx.x * 1024;
    int s = 0;
    for (int i = threadIdx.x; i < 1024; i += 256) {
        int idx = base + i;
        s += (idx < n) ? deg[idx] : 0;
    }
    __shared__ int ws4[4];
    int lane = threadIdx.x & 63, w = threadIdx.x >> 6;
#pragma unroll
    for (int off = 32; off; off >>= 1) s += __shfl_down(s, off);
    if (lane == 0) ws4[w] = s;
    __syncthreads();
    if (threadIdx.x == 0)
        partial[blockIdx.x] = ws4[0] + ws4[1] + ws4[2] + ws4[3];
}

// phase 2: single block scans <=256 partials, writes rowptr[n]=E
__global__ void scan_phase2(int* __restrict__ partial, int nb,
                            int* __restrict__ rowptr, int n, int E) {
    int tid = threadIdx.x;
    int v = (tid < nb) ? partial[tid] : 0;
    int ex = block_excl_scan_256(v, tid);
    if (tid < nb) partial[tid] = ex;
    if (tid == 0) rowptr[n] = E;
}

// phase 3: per-chunk local scan + chunk offset -> rowptr/cursor/inv_deg
__global__ void scan_phase3(const int* __restrict__ deg,
                            const int* __restrict__ partial,
                            int* __restrict__ rowptr, int* __restrict__ cursor,
                            float* __restrict__ inv_deg, int n) {
    int base = blockIdx.x * 1024 + threadIdx.x * 4;
    int d[4];
#pragma unroll
    for (int j = 0; j < 4; ++j) {
        int idx = base + j;
        d[j] = (idx < n) ? deg[idx] : 0;
    }
    int tsum = d[0] + d[1] + d[2] + d[3];
    int ex = block_excl_scan_256(tsum, threadIdx.x);
    int run = partial[blockIdx.x] + ex;
#pragma unroll
    for (int j = 0; j < 4; ++j) {
        int idx = base + j;
        if (idx < n) {
            rowptr[idx] = run;
            cursor[idx] = run;
            inv_deg[idx] = 1.0f / (float)max(d[j], 1);
        }
        run += d[j];
    }
}

__global__ void fill_csr_kernel(const int* __restrict__ src,
                                const int* __restrict__ dst,
                                int* __restrict__ cursor,
                                int* __restrict__ csr_src, int E) {
    int e = blockIdx.x * blockDim.x + threadIdx.x;
    if (e < E) {
        int d = dst[e];
        int pos = atomicAdd(&cursor[d], 1);
        csr_src[pos] = src[e];
    }
}

// --------------------------- input split ----------------------------------
__global__ void x_split_kernel(const float* __restrict__ x,
                               unsigned short* __restrict__ hhi,
                               unsigned short* __restrict__ hlo, int n4) {
    int i = blockIdx.x * blockDim.x + threadIdx.x;
    if (i >= n4) return;
    float4 v = ((const float4*)x)[i];
    unsigned short h[4], l[4];
    split_bf(v.x, h[0], l[0]);
    split_bf(v.y, h[1], l[1]);
    split_bf(v.z, h[2], l[2]);
    split_bf(v.w, h[3], l[3]);
    ((uint2*)hhi)[i] = make_uint2((unsigned)h[0] | ((unsigned)h[1] << 16),
                                  (unsigned)h[2] | ((unsigned)h[3] << 16));
    ((uint2*)hlo)[i] = make_uint2((unsigned)l[0] | ((unsigned)l[1] << 16),
                                  (unsigned)l[2] | ((unsigned)l[3] << 16));
}

// Pre-split W into fragment-ordered bf16 hi/lo:
// per (layer,source): [step(8)][tile(16)][g(4)][col(16)][j(8)]
__global__ void presplit_w_kernel(const float* __restrict__ Wl,
                                  const float* __restrict__ Wr,
                                  unsigned short* __restrict__ Wf_hi,
                                  unsigned short* __restrict__ Wf_lo,
                                  int total) {
    int idx = blockIdx.x * blockDim.x + threadIdx.x;
    if (idx >= total) return;
    int l = idx >> 17;
    int rem = idx & 131071;
    int s = rem >> 16;
    int kc = rem & 65535;
    int k = kc >> 8, c = kc & 255;
    const float* W = s ? Wr : Wl;
    float w = W[((size_t)l * 256 + k) * 256 + c];
    unsigned short hi, lo;
    split_bf(w, hi, lo);
    int step = k >> 5, g = (k >> 3) & 3, j = k & 7;
    int tile = c >> 4, col = c & 15;
    int fi = ((l * 2 + s) << 16) +
             ((((step * 16 + tile) * 4 + g) * 16 + col) * 8 + j);
    Wf_hi[fi] = hi;
    Wf_lo[fi] = lo;
}

// ------------------------------ aggregation -------------------------------
// One wave per dst node; gathers bf16(hi) rows, fp32 accumulate, writes the
// mean pre-split (hi/lo) into the node's 1KB slot in d_out.
__global__ void aggregate_kernel(const unsigned short* __restrict__ h_hi,
                                 const int* __restrict__ rowptr,
                                 const int* __restrict__ csr_src,
                                 const float* __restrict__ inv_deg,
                                 unsigned short* aggout, int n) {
    int wave = threadIdx.x >> 6;
    int lane = threadIdx.x & 63;
    int v = blockIdx.x * 4 + wave;
    if (v >= n) return;
    int beg = rowptr[v], end = rowptr[v + 1];
    const uint2* h2 = (const uint2*)h_hi;
    float a0 = 0.f, a1 = 0.f, a2 = 0.f, a3 = 0.f;
    for (int e = beg; e < end; ++e) {
        int u = csr_src[e];
        uint2 t = h2[(size_t)u * 64 + lane];
        a0 += __uint_as_float(t.x << 16);
        a1 += __uint_as_float(t.x & 0xffff0000u);
        a2 += __uint_as_float(t.y << 16);
        a3 += __uint_as_float(t.y & 0xffff0000u);
    }
    float sc = inv_deg[v];
    unsigned short h[4], l[4];
    split_bf(a0 * sc, h[0], l[0]);
    split_bf(a1 * sc, h[1], l[1]);
    split_bf(a2 * sc, h[2], l[2]);
    split_bf(a3 * sc, h[3], l[3]);
    unsigned short* prow = aggout + (size_t)v * 512;
    *(uint2*)&prow[lane * 4] =
        make_uint2((unsigned)h[0] | ((unsigned)h[1] << 16),
                   (unsigned)h[2] | ((unsigned)h[3] << 16));
    *(uint2*)&prow[256 + lane * 4] =
        make_uint2((unsigned)l[0] | ((unsigned)l[1] << 16),
                   (unsigned)l[2] | ((unsigned)l[3] << 16));
}

// ------------------------------- MFMA GEMM --------------------------------
// C[r0:r0+128][0:256] = agg@Wl + h@Wr + b. agg pair in d_out slots (stride
// 512, lo at +256); h pair in ws (stride 256). mode 0: relu + write h pair
// (in place per stripe). mode 1: write fp32 to d_out (in place over agg).
__global__ __launch_bounds__(256) void sage_gemm_mfma(
    const unsigned short* agg, const unsigned short* __restrict__ h_hi,
    const unsigned short* __restrict__ h_lo, unsigned short* out_hi,
    unsigned short* out_lo, float* out_f,
    const unsigned short* __restrict__ Wf_hi,
    const unsigned short* __restrict__ Wf_lo,
    const float* __restrict__ bias, int M, int mode) {
    __shared__ __align__(16) unsigned short Ah[2][4][129][8];    // 16.5 KB
    __shared__ __align__(16) unsigned short Ws[2][16][4][16][8]; // 32 KB

    const int tid = threadIdx.x;
    const int wave = tid >> 6, lane = tid & 63;
    const int l15 = lane & 15, lg = lane >> 4;
    const int r0 = blockIdx.x * 128;

    f32x4 acc[2][16];
#pragma unroll
    for (int rt = 0; rt < 2; ++rt)
#pragma unroll
        for (int t = 0; t < 16; ++t) acc[rt][t] = (f32x4)(0.0f);

#pragma unroll
    for (int s = 0; s < 2; ++s) {
        const unsigned short* Ahi_g = s ? h_hi : agg;
        const unsigned short* Alo_g = s ? h_lo : (agg + 256);
        const int strideA = s ? 256 : 512;
        const unsigned short* Whg = Wf_hi + s * 65536;
        const unsigned short* Wlg = Wf_lo + s * 65536;
        for (int k0 = 0; k0 < 256; k0 += 32) {
            // ---- stage A chunk: pure tiled copy ----
#pragma unroll
            for (int i = 0; i < 2; ++i) {
                int idx = tid + i * 256;     // 0..511
                int row = idx >> 2, q = idx & 3;
                int grow = r0 + row;
                uint4 vh = make_uint4(0, 0, 0, 0), vl = make_uint4(0, 0, 0, 0);
                if (grow < M) {
                    const unsigned short* ph =
                        Ahi_g + (size_t)grow * strideA + k0 + q * 8;
                    const unsigned short* pl =
                        Alo_g + (size_t)grow * strideA + k0 + q * 8;
                    vh = *(const uint4*)ph;
                    vl = *(const uint4*)pl;
                }
                *(uint4*)&Ah[0][q][row][0] = vh;
                *(uint4*)&Ah[1][q][row][0] = vl;
            }
            // ---- stage W chunk: linear copy ----
            {
                const uint4* gh = (const uint4*)(Whg + (k0 >> 5) * 8192);
                const uint4* gl = (const uint4*)(Wlg + (k0 >> 5) * 8192);
                uint4* lh = (uint4*)&Ws[0][0][0][0][0];
                uint4* ll = (uint4*)&Ws[1][0][0][0][0];
#pragma unroll
                for (int i = 0; i < 4; ++i) {
                    lh[i * 256 + tid] = gh[i * 256 + tid];
                    ll[i * 256 + tid] = gl[i * 256 + tid];
                }
            }
            __syncthreads();
            // ---- compute: 3-term split product ----
            bf16x8 ahi[2], alo[2];
#pragma unroll
            for (int rt = 0; rt < 2; ++rt) {
                int row = wave * 32 + rt * 16 + l15;
                ahi[rt] = *(const bf16x8*)&Ah[0][lg][row][0];
                alo[rt] = *(const bf16x8*)&Ah[1][lg][row][0];
            }
#pragma unroll
            for (int t = 0; t < 16; ++t) {
                bf16x8 bhi = *(const bf16x8*)&Ws[0][t][lg][l15][0];
                bf16x8 blo = *(const bf16x8*)&Ws[1][t][lg][l15][0];
#pragma unroll
                for (int rt = 0; rt < 2; ++rt) {
                    acc[rt][t] = __builtin_amdgcn_mfma_f32_16x16x32_bf16(
                        ahi[rt], bhi, acc[rt][t], 0, 0, 0);
                    acc[rt][t] = __builtin_amdgcn_mfma_f32_16x16x32_bf16(
                        alo[rt], bhi, acc[rt][t], 0, 0, 0);
                    acc[rt][t] = __builtin_amdgcn_mfma_f32_16x16x32_bf16(
                        ahi[rt], blo, acc[rt][t], 0, 0, 0);
                }
            }
            __syncthreads();
        }
    }

    // ---- epilogue ----
    float bv[16];
#pragma unroll
    for (int t = 0; t < 16; ++t) bv[t] = bias[t * 16 + l15];
#pragma unroll
    for (int rt = 0; rt < 2; ++rt) {
#pragma unroll
        for (int r = 0; r < 4; ++r) {
            int grow = r0 + wave * 32 + rt * 16 + lg * 4 + r;
            if (grow >= M) continue;
#pragma unroll
            for (int t = 0; t < 16; ++t) {
                float o = acc[rt][t][r] + bv[t];
                int col = t * 16 + l15;
                if (mode == 0) {
                    o = fmaxf(o, 0.0f);
                    unsigned short hi, lo;
                    split_bf(o, hi, lo);
                    out_hi[(size_t)grow * 256 + col] = hi;
                    out_lo[(size_t)grow * 256 + col] = lo;
                } else {
                    out_f[(size_t)grow * 256 + col] = o;
                }
            }
        }
    }
}

// --------------------------------- launch ---------------------------------
extern "C" void kernel_launch(void* const* d_in, const int* in_sizes, int n_in,
                              void* d_out, int out_size, void* d_ws, size_t ws_size,
                              hipStream_t stream) {
    const int D = 256;
    const int N = in_sizes[0] / D;
    const int E = in_sizes[1] / 2;
    const int L = in_sizes[2] / (D * D);

    const float* x  = (const float*)d_in[0];
    const int*   ei = (const int*)d_in[1];
    const float* Wl = (const float*)d_in[2];
    const float* Wr = (const float*)d_in[3];
    const float* b  = (const float*)d_in[4];
    const int* src = ei;
    const int* dst = ei + E;

    size_t off = 0;
    auto alloc = [&](size_t bytes) {
        void* p = (char*)d_ws + off;
        off += (bytes + 255) & ~(size_t)255;
        return p;
    };
    int*   deg     = (int*)alloc((size_t)N * 4);
    int*   rowptr  = (int*)alloc((size_t)(N + 1) * 4);
    int*   cursor  = (int*)alloc((size_t)N * 4);
    float* inv_deg = (float*)alloc((size_t)N * 4);
    int*   csr_src = (int*)alloc((size_t)E * 4);
    int*   partial = (int*)alloc(256 * 4);
    unsigned short* h16hi = (unsigned short*)alloc((size_t)N * D * 2);
    unsigned short* h16lo = (unsigned short*)alloc((size_t)N * D * 2);
    unsigned short* Wf_hi = (unsigned short*)alloc((size_t)L * 2 * 65536 * 2);
    unsigned short* Wf_lo = (unsigned short*)alloc((size_t)L * 2 * 65536 * 2);
    (void)ws_size;

    unsigned short* aggp = (unsigned short*)d_out;  // [N][512]: hi | lo slots
    float* outf = (float*)d_out;

    const int scan_blocks = (N + 1023) / 1024;

    // CSR build
    hipMemsetAsync(deg, 0, (size_t)N * 4, stream);
    hipLaunchKernelGGL(count_deg_kernel, dim3((E + 255) / 256), dim3(256), 0,
                       stream, dst, deg, E);
    hipLaunchKernelGGL(scan_phase1, dim3(scan_blocks), dim3(256), 0, stream,
                       deg, partial, N);
    hipLaunchKernelGGL(scan_phase2, dim3(1), dim3(256), 0, stream,
                       partial, scan_blocks, rowptr, N, E);
    hipLaunchKernelGGL(scan_phase3, dim3(scan_blocks), dim3(256), 0, stream,
                       deg, partial, rowptr, cursor, inv_deg, N);
    hipLaunchKernelGGL(fill_csr_kernel, dim3((E + 255) / 256), dim3(256), 0,
                       stream, src, dst, cursor, csr_src, E);

    // weight pre-split + x split
    int wtotal = L * 2 * 65536;
    hipLaunchKernelGGL(presplit_w_kernel, dim3((wtotal + 255) / 256), dim3(256),
                       0, stream, Wl, Wr, Wf_hi, Wf_lo, wtotal);
    hipLaunchKernelGGL(x_split_kernel, dim3((N * D / 4 + 255) / 256), dim3(256),
                       0, stream, x, h16hi, h16lo, N * D / 4);

    const int gemm_blocks = (N + 127) / 128;
    for (int l = 0; l < L; ++l) {
        hipLaunchKernelGGL(aggregate_kernel, dim3((N + 3) / 4), dim3(256), 0,
                           stream, h16hi, rowptr, csr_src, inv_deg, aggp, N);
        int mode = (l < L - 1) ? 0 : 1;
        hipLaunchKernelGGL(sage_gemm_mfma, dim3(gemm_blocks), dim3(256), 0,
                           stream, aggp, h16hi, h16lo, h16hi, h16lo, outf,
                           Wf_hi + (size_t)l * 2 * 65536,
                           Wf_lo + (size_t)l * 2 * 65536,
                           b + (size_t)l * D, N, mode);
    }
}

// Round 4
// 482.407 us; speedup vs baseline: 2.3542x; 1.3058x over previous
//
#include <hip/hip_runtime.h>

// ---------------------------------------------------------------------------
// GraphSAGE (mean) x3: h' = mean_agg(h)@Wl + h@Wr + b, relu between layers.
// R4: fp16 single-product MFMA (no hi/lo split); linearity trick:
//   Zl = h@Wl, Zr = h@Wr + b  (dual-output GEMM, shared A staging)
//   h' = relu(mean-gather(Zl) + Zr)   (combine kernel)
// Zr kept fp32 in d_out; final combine overwrites d_out rows in place.
// ---------------------------------------------------------------------------

typedef __attribute__((ext_vector_type(8))) _Float16 f16x8;
typedef __attribute__((ext_vector_type(4))) float f32x4;

// ------------------------------- CSR build --------------------------------
__global__ void count_deg_kernel(const int* __restrict__ dst,
                                 int* __restrict__ deg, int E) {
    int e = blockIdx.x * blockDim.x + threadIdx.x;
    if (e < E) atomicAdd(&deg[dst[e]], 1);
}

__device__ __forceinline__ int block_excl_scan_256(int v, int tid) {
    int lane = tid & 63, w = tid >> 6;
    int x = v;
#pragma unroll
    for (int off = 1; off < 64; off <<= 1) {
        int y = __shfl_up(x, off);
        if (lane >= off) x += y;
    }
    __shared__ int wsum[4], woff[4];
    if (lane == 63) wsum[w] = x;
    __syncthreads();
    if (tid == 0) {
        int a = 0;
#pragma unroll
        for (int i = 0; i < 4; ++i) { woff[i] = a; a += wsum[i]; }
    }
    __syncthreads();
    return woff[w] + x - v;
}

__global__ void scan_phase1(const int* __restrict__ deg,
                            int* __restrict__ partial, int n) {
    int base = blockIdx.x * 1024;
    int s = 0;
    for (int i = threadIdx.x; i < 1024; i += 256) {
        int idx = base + i;
        s += (idx < n) ? deg[idx] : 0;
    }
    __shared__ int ws4[4];
    int lane = threadIdx.x & 63, w = threadIdx.x >> 6;
#pragma unroll
    for (int off = 32; off; off >>= 1) s += __shfl_down(s, off);
    if (lane == 0) ws4[w] = s;
    __syncthreads();
    if (threadIdx.x == 0)
        partial[blockIdx.x] = ws4[0] + ws4[1] + ws4[2] + ws4[3];
}

__global__ void scan_phase2(int* __restrict__ partial, int nb,
                            int* __restrict__ rowptr, int n, int E) {
    int tid = threadIdx.x;
    int v = (tid < nb) ? partial[tid] : 0;
    int ex = block_excl_scan_256(v, tid);
    if (tid < nb) partial[tid] = ex;
    if (tid == 0) rowptr[n] = E;
}

__global__ void scan_phase3(const int* __restrict__ deg,
                            const int* __restrict__ partial,
                            int* __restrict__ rowptr, int* __restrict__ cursor,
                            float* __restrict__ inv_deg, int n) {
    int base = blockIdx.x * 1024 + threadIdx.x * 4;
    int d[4];
#pragma unroll
    for (int j = 0; j < 4; ++j) {
        int idx = base + j;
        d[j] = (idx < n) ? deg[idx] : 0;
    }
    int tsum = d[0] + d[1] + d[2] + d[3];
    int ex = block_excl_scan_256(tsum, threadIdx.x);
    int run = partial[blockIdx.x] + ex;
#pragma unroll
    for (int j = 0; j < 4; ++j) {
        int idx = base + j;
        if (idx < n) {
            rowptr[idx] = run;
            cursor[idx] = run;
            inv_deg[idx] = 1.0f / (float)max(d[j], 1);
        }
        run += d[j];
    }
}

__global__ void fill_csr_kernel(const int* __restrict__ src,
                                const int* __restrict__ dst,
                                int* __restrict__ cursor,
                                int* __restrict__ csr_src, int E) {
    int e = blockIdx.x * blockDim.x + threadIdx.x;
    if (e < E) {
        int d = dst[e];
        int pos = atomicAdd(&cursor[d], 1);
        csr_src[pos] = src[e];
    }
}

// ----------------------- W -> fp16 fragment order -------------------------
// per (layer,source): [k0chunk(8)][tile(16)][g(4)][col(16)][j(8)]
__global__ void presplit_w_kernel(const float* __restrict__ Wl,
                                  const float* __restrict__ Wr,
                                  _Float16* __restrict__ Wf, int total) {
    int idx = blockIdx.x * blockDim.x + threadIdx.x;
    if (idx >= total) return;
    int l = idx >> 17;
    int rem = idx & 131071;
    int s = rem >> 16;
    int kc = rem & 65535;
    int k = kc >> 8, c = kc & 255;
    const float* W = s ? Wr : Wl;
    float w = W[((size_t)l * 256 + k) * 256 + c];
    int k0c = k >> 5, g = (k >> 3) & 3, j = k & 7;
    int tile = c >> 4, col = c & 15;
    int fi = (l * 2 + s) * 65536 + k0c * 8192 + ((tile * 4 + g) * 16 + col) * 8 + j;
    Wf[fi] = (_Float16)w;
}

// --------------------------- dual-output GEMM -----------------------------
// Block: 64 rows x 256 cols. 4 waves; wave w: rows (w&1)*32..+31,
// cols (w>>1)*128..+127. Zl = A@Wl (fp16), Zr = A@Wr + b (fp32, d_out).
// Layer 0 reads fp32 x, later layers fp16 h.
__global__ __launch_bounds__(256) void dual_gemm(
    const _Float16* __restrict__ hsrc, const float* __restrict__ xsrc,
    int f32src, _Float16* __restrict__ zl, float* __restrict__ zr,
    const _Float16* __restrict__ Wf_l, const float* __restrict__ bias, int M) {
    __shared__ __align__(16) _Float16 Ah[4][65][8];        // 8.3 KB
    __shared__ __align__(16) _Float16 Ws[2][16][4][16][8]; // 32 KB

    const int tid = threadIdx.x;
    const int wave = tid >> 6, lane = tid & 63;
    const int l15 = lane & 15, lg = lane >> 4;
    const int wr = (wave & 1) * 32;
    const int wc = (wave >> 1) * 128;
    const int r0 = blockIdx.x * 64;

    f32x4 accl[2][8], accr[2][8];
#pragma unroll
    for (int rt = 0; rt < 2; ++rt)
#pragma unroll
        for (int t = 0; t < 8; ++t) {
            accl[rt][t] = (f32x4)(0.0f);
            accr[rt][t] = (f32x4)(0.0f);
        }

    const int s_row = tid >> 2, s_q = tid & 3;

    for (int k0 = 0; k0 < 256; k0 += 32) {
        // ---- stage A (64 rows x 32 k) ----
        {
            int grow = r0 + s_row;
            f16x8 av = (f16x8)(_Float16)0;
            if (grow < M) {
                if (f32src) {
                    const float4* p =
                        (const float4*)&xsrc[(size_t)grow * 256 + k0 + s_q * 8];
                    float4 v0 = p[0], v1 = p[1];
                    av[0] = (_Float16)v0.x; av[1] = (_Float16)v0.y;
                    av[2] = (_Float16)v0.z; av[3] = (_Float16)v0.w;
                    av[4] = (_Float16)v1.x; av[5] = (_Float16)v1.y;
                    av[6] = (_Float16)v1.z; av[7] = (_Float16)v1.w;
                } else {
                    av = *(const f16x8*)&hsrc[(size_t)grow * 256 + k0 + s_q * 8];
                }
            }
            *(f16x8*)&Ah[s_q][s_row][0] = av;
        }
        // ---- stage W chunk (both Wl,Wr; pre-fragment-ordered linear copy) ----
        {
            const uint4* ws0 = (const uint4*)(Wf_l + (k0 >> 5) * 8192);
            const uint4* ws1 = (const uint4*)(Wf_l + 65536 + (k0 >> 5) * 8192);
            uint4* ld = (uint4*)&Ws[0][0][0][0][0];
#pragma unroll
            for (int i = 0; i < 4; ++i) ld[i * 256 + tid] = ws0[i * 256 + tid];
#pragma unroll
            for (int i = 0; i < 4; ++i)
                ld[1024 + i * 256 + tid] = ws1[i * 256 + tid];
        }
        __syncthreads();
        // ---- compute ----
        f16x8 a[2];
        a[0] = *(const f16x8*)&Ah[lg][wr + l15][0];
        a[1] = *(const f16x8*)&Ah[lg][wr + 16 + l15][0];
#pragma unroll
        for (int t = 0; t < 8; ++t) {
            int tg = (wc >> 4) + t;
            f16x8 bl = *(const f16x8*)&Ws[0][tg][lg][l15][0];
            f16x8 br = *(const f16x8*)&Ws[1][tg][lg][l15][0];
#pragma unroll
            for (int rt = 0; rt < 2; ++rt) {
                accl[rt][t] = __builtin_amdgcn_mfma_f32_16x16x32_f16(
                    a[rt], bl, accl[rt][t], 0, 0, 0);
                accr[rt][t] = __builtin_amdgcn_mfma_f32_16x16x32_f16(
                    a[rt], br, accr[rt][t], 0, 0, 0);
            }
        }
        __syncthreads();
    }

    // ---- epilogue: Zl fp16, Zr fp32 + bias ----
    float bv[8];
#pragma unroll
    for (int t = 0; t < 8; ++t) bv[t] = bias[wc + t * 16 + l15];
#pragma unroll
    for (int rt = 0; rt < 2; ++rt) {
#pragma unroll
        for (int r = 0; r < 4; ++r) {
            int grow = r0 + wr + rt * 16 + lg * 4 + r;
            if (grow >= M) continue;
#pragma unroll
            for (int t = 0; t < 8; ++t) {
                int col = wc + t * 16 + l15;
                zl[(size_t)grow * 256 + col] = (_Float16)accl[rt][t][r];
                zr[(size_t)grow * 256 + col] = accr[rt][t][r] + bv[t];
            }
        }
    }
}

// ------------------------------- combine ----------------------------------
// h'[v] = relu?( mean_{u in N(v)} Zl[u] + Zr[v] ).  One wave per node;
// lanes split in halves handling alternating edges (2 gathers in flight),
// 16 B/lane per row, shfl_xor(32) cross-half reduce.
__global__ void combine_kernel(const _Float16* __restrict__ zl,
                               const float* __restrict__ zr,
                               const int* __restrict__ rowptr,
                               const int* __restrict__ csr_src,
                               const float* __restrict__ inv_deg,
                               _Float16* __restrict__ hout,
                               float* __restrict__ fout, int n, int mode) {
    int wave = threadIdx.x >> 6, lane = threadIdx.x & 63;
    int v = blockIdx.x * 4 + wave;
    if (v >= n) return;
    int half = lane >> 5, li = lane & 31;
    int beg = rowptr[v], end = rowptr[v + 1];
    float acc[8] = {0.f, 0.f, 0.f, 0.f, 0.f, 0.f, 0.f, 0.f};
    for (int e = beg + half; e < end; e += 2) {
        int u = csr_src[e];
        f16x8 t = *(const f16x8*)&zl[(size_t)u * 256 + li * 8];
#pragma unroll
        for (int j = 0; j < 8; ++j) acc[j] += (float)t[j];
    }
#pragma unroll
    for (int j = 0; j < 8; ++j) acc[j] += __shfl_xor(acc[j], 32);
    if (half == 0) {
        float sc = inv_deg[v];
        const float4* zp = (const float4*)&zr[(size_t)v * 256 + li * 8];
        float4 z0 = zp[0], z1 = zp[1];
        float o[8];
        o[0] = acc[0] * sc + z0.x; o[1] = acc[1] * sc + z0.y;
        o[2] = acc[2] * sc + z0.z; o[3] = acc[3] * sc + z0.w;
        o[4] = acc[4] * sc + z1.x; o[5] = acc[5] * sc + z1.y;
        o[6] = acc[6] * sc + z1.z; o[7] = acc[7] * sc + z1.w;
        if (mode == 0) {
            f16x8 p;
#pragma unroll
            for (int j = 0; j < 8; ++j) p[j] = (_Float16)fmaxf(o[j], 0.0f);
            *(f16x8*)&hout[(size_t)v * 256 + li * 8] = p;
        } else {
            float4* op = (float4*)&fout[(size_t)v * 256 + li * 8];
            op[0] = make_float4(o[0], o[1], o[2], o[3]);
            op[1] = make_float4(o[4], o[5], o[6], o[7]);
        }
    }
}

// --------------------------------- launch ---------------------------------
extern "C" void kernel_launch(void* const* d_in, const int* in_sizes, int n_in,
                              void* d_out, int out_size, void* d_ws, size_t ws_size,
                              hipStream_t stream) {
    const int D = 256;
    const int N = in_sizes[0] / D;
    const int E = in_sizes[1] / 2;
    const int L = in_sizes[2] / (D * D);

    const float* x  = (const float*)d_in[0];
    const int*   ei = (const int*)d_in[1];
    const float* Wl = (const float*)d_in[2];
    const float* Wr = (const float*)d_in[3];
    const float* b  = (const float*)d_in[4];
    const int* src = ei;
    const int* dst = ei + E;

    size_t off = 0;
    auto alloc = [&](size_t bytes) {
        void* p = (char*)d_ws + off;
        off += (bytes + 255) & ~(size_t)255;
        return p;
    };
    int*   deg     = (int*)alloc((size_t)N * 4);
    int*   rowptr  = (int*)alloc((size_t)(N + 1) * 4);
    int*   cursor  = (int*)alloc((size_t)N * 4);
    float* inv_deg = (float*)alloc((size_t)N * 4);
    int*   csr_src = (int*)alloc((size_t)E * 4);
    int*   partial = (int*)alloc(256 * 4);
    _Float16* hA = (_Float16*)alloc((size_t)N * D * 2);
    _Float16* zl = (_Float16*)alloc((size_t)N * D * 2);
    _Float16* Wf = (_Float16*)alloc((size_t)L * 2 * 65536 * 2);
    (void)ws_size;

    float* zr = (float*)d_out;

    const int scan_blocks = (N + 1023) / 1024;

    // CSR build
    hipMemsetAsync(deg, 0, (size_t)N * 4, stream);
    hipLaunchKernelGGL(count_deg_kernel, dim3((E + 255) / 256), dim3(256), 0,
                       stream, dst, deg, E);
    hipLaunchKernelGGL(scan_phase1, dim3(scan_blocks), dim3(256), 0, stream,
                       deg, partial, N);
    hipLaunchKernelGGL(scan_phase2, dim3(1), dim3(256), 0, stream,
                       partial, scan_blocks, rowptr, N, E);
    hipLaunchKernelGGL(scan_phase3, dim3(scan_blocks), dim3(256), 0, stream,
                       deg, partial, rowptr, cursor, inv_deg, N);
    hipLaunchKernelGGL(fill_csr_kernel, dim3((E + 255) / 256), dim3(256), 0,
                       stream, src, dst, cursor, csr_src, E);

    // W -> fp16 fragment order
    int wtotal = L * 2 * 65536;
    hipLaunchKernelGGL(presplit_w_kernel, dim3((wtotal + 255) / 256), dim3(256),
                       0, stream, Wl, Wr, Wf, wtotal);

    const int gemm_blocks = (N + 63) / 64;
    const int comb_blocks = (N + 3) / 4;
    for (int l = 0; l < L; ++l) {
        hipLaunchKernelGGL(dual_gemm, dim3(gemm_blocks), dim3(256), 0, stream,
                           hA, x, (l == 0) ? 1 : 0, zl, zr,
                           Wf + (size_t)l * 131072, b + (size_t)l * D, N);
        hipLaunchKernelGGL(combine_kernel, dim3(comb_blocks), dim3(256), 0,
                           stream, zl, zr, rowptr, csr_src, inv_deg,
                           hA, zr, N, (l < L - 1) ? 0 : 1);
    }
}

// Round 5
// 441.528 us; speedup vs baseline: 2.5722x; 1.0926x over previous
//
#include <hip/hip_runtime.h>

// ---------------------------------------------------------------------------
// GraphSAGE (mean) x3: h' = relu(mean_agg(h)@Wl + h@Wr + b).
// R5: linearity trick (Zl=h@Wl, Zr=h@Wr+b fused dual GEMM, then combine).
//  - GEMM: A-stripe staged to LDS ONCE (1 barrier/block), W read directly
//    global->VGPR from fragment-ordered fp16 (L1/L2-hot). Zl,Zr fp16.
//  - combine: 2x-unrolled half-wave gather of Zl + Zr + relu.
//  - hA (fp16 h) aliases d_out; final combine overwrites d_out with fp32.
// ---------------------------------------------------------------------------

typedef __attribute__((ext_vector_type(8))) _Float16 f16x8;
typedef __attribute__((ext_vector_type(4))) float f32x4;

// ------------------------------- CSR build --------------------------------
__global__ void count_deg_kernel(const int* __restrict__ dst,
                                 int* __restrict__ deg, int E) {
    int e = blockIdx.x * blockDim.x + threadIdx.x;
    if (e < E) atomicAdd(&deg[dst[e]], 1);
}

__device__ __forceinline__ int block_excl_scan_256(int v, int tid) {
    int lane = tid & 63, w = tid >> 6;
    int x = v;
#pragma unroll
    for (int off = 1; off < 64; off <<= 1) {
        int y = __shfl_up(x, off);
        if (lane >= off) x += y;
    }
    __shared__ int wsum[4], woff[4];
    if (lane == 63) wsum[w] = x;
    __syncthreads();
    if (tid == 0) {
        int a = 0;
#pragma unroll
        for (int i = 0; i < 4; ++i) { woff[i] = a; a += wsum[i]; }
    }
    __syncthreads();
    return woff[w] + x - v;
}

__global__ void scan_phase1(const int* __restrict__ deg,
                            int* __restrict__ partial, int n) {
    int base = blockIdx.x * 1024;
    int s = 0;
    for (int i = threadIdx.x; i < 1024; i += 256) {
        int idx = base + i;
        s += (idx < n) ? deg[idx] : 0;
    }
    __shared__ int ws4[4];
    int lane = threadIdx.x & 63, w = threadIdx.x >> 6;
#pragma unroll
    for (int off = 32; off; off >>= 1) s += __shfl_down(s, off);
    if (lane == 0) ws4[w] = s;
    __syncthreads();
    if (threadIdx.x == 0)
        partial[blockIdx.x] = ws4[0] + ws4[1] + ws4[2] + ws4[3];
}

__global__ void scan_phase2(int* __restrict__ partial, int nb,
                            int* __restrict__ rowptr, int n, int E) {
    int tid = threadIdx.x;
    int v = (tid < nb) ? partial[tid] : 0;
    int ex = block_excl_scan_256(v, tid);
    if (tid < nb) partial[tid] = ex;
    if (tid == 0) rowptr[n] = E;
}

__global__ void scan_phase3(const int* __restrict__ deg,
                            const int* __restrict__ partial,
                            int* __restrict__ rowptr, int* __restrict__ cursor,
                            float* __restrict__ inv_deg, int n) {
    int base = blockIdx.x * 1024 + threadIdx.x * 4;
    int d[4];
#pragma unroll
    for (int j = 0; j < 4; ++j) {
        int idx = base + j;
        d[j] = (idx < n) ? deg[idx] : 0;
    }
    int tsum = d[0] + d[1] + d[2] + d[3];
    int ex = block_excl_scan_256(tsum, threadIdx.x);
    int run = partial[blockIdx.x] + ex;
#pragma unroll
    for (int j = 0; j < 4; ++j) {
        int idx = base + j;
        if (idx < n) {
            rowptr[idx] = run;
            cursor[idx] = run;
            inv_deg[idx] = 1.0f / (float)max(d[j], 1);
        }
        run += d[j];
    }
}

__global__ void fill_csr_kernel(const int* __restrict__ src,
                                const int* __restrict__ dst,
                                int* __restrict__ cursor,
                                int* __restrict__ csr_src, int E) {
    int e = blockIdx.x * blockDim.x + threadIdx.x;
    if (e < E) {
        int d = dst[e];
        int pos = atomicAdd(&cursor[d], 1);
        csr_src[pos] = src[e];
    }
}

// ----------------------- W -> fp16 fragment order -------------------------
// per (layer,source): [k0chunk(8)][tile(16)][g(4)][col(16)][j(8)]
__global__ void presplit_w_kernel(const float* __restrict__ Wl,
                                  const float* __restrict__ Wr,
                                  _Float16* __restrict__ Wf, int total) {
    int idx = blockIdx.x * blockDim.x + threadIdx.x;
    if (idx >= total) return;
    int l = idx >> 17;
    int rem = idx & 131071;
    int s = rem >> 16;
    int kc = rem & 65535;
    int k = kc >> 8, c = kc & 255;
    const float* W = s ? Wr : Wl;
    float w = W[((size_t)l * 256 + k) * 256 + c];
    int k0c = k >> 5, g = (k >> 3) & 3, j = k & 7;
    int tile = c >> 4, col = c & 15;
    int fi = (l * 2 + s) * 65536 + k0c * 8192 + ((tile * 4 + g) * 16 + col) * 8 + j;
    Wf[fi] = (_Float16)w;
}

// --------------------------- dual-output GEMM -----------------------------
// Block: 64 rows x 256 cols, 4 waves (wave: rows (w&1)*32..+31, cols
// (w>>1)*128..+127). A staged to LDS once; W fragments straight from global.
// Zl = A@Wl, Zr = A@Wr + b, both fp16.
__global__ __launch_bounds__(256) void dual_gemm(
    const _Float16* __restrict__ hsrc, const float* __restrict__ xsrc,
    int f32src, _Float16* __restrict__ zl, _Float16* __restrict__ zr,
    const _Float16* __restrict__ Wf_l, const float* __restrict__ bias, int M) {
    __shared__ __align__(16) _Float16 Ah[32][65][8];  // 33 KB, g=k>>3

    const int tid = threadIdx.x;
    const int r0 = blockIdx.x * 64;

    // ---- stage full A stripe (64x256) once ----
#pragma unroll
    for (int i = 0; i < 8; ++i) {
        int idx = i * 256 + tid;        // uint4 index, 0..2047
        int row = idx >> 5;             // 0..63
        int g = idx & 31;               // k-group (k = g*8..g*8+7)
        int grow = r0 + row;
        f16x8 v = (f16x8)(_Float16)0;
        if (grow < M) {
            if (f32src) {
                const float4* p = (const float4*)&xsrc[(size_t)grow * 256 + g * 8];
                float4 v0 = p[0], v1 = p[1];
                v[0] = (_Float16)v0.x; v[1] = (_Float16)v0.y;
                v[2] = (_Float16)v0.z; v[3] = (_Float16)v0.w;
                v[4] = (_Float16)v1.x; v[5] = (_Float16)v1.y;
                v[6] = (_Float16)v1.z; v[7] = (_Float16)v1.w;
            } else {
                v = *(const f16x8*)&hsrc[(size_t)grow * 256 + g * 8];
            }
        }
        *(f16x8*)&Ah[g][row][0] = v;
    }
    __syncthreads();

    const int wave = tid >> 6, lane = tid & 63;
    const int l15 = lane & 15, lg = lane >> 4;
    const int wr = (wave & 1) * 32;
    const int wc = (wave >> 1) * 128;

    f32x4 accl[2][8], accr[2][8];
#pragma unroll
    for (int rt = 0; rt < 2; ++rt)
#pragma unroll
        for (int t = 0; t < 8; ++t) {
            accl[rt][t] = (f32x4)(0.0f);
            accr[rt][t] = (f32x4)(0.0f);
        }

#pragma unroll
    for (int k0 = 0; k0 < 256; k0 += 32) {
        f16x8 a0 = *(const f16x8*)&Ah[(k0 >> 3) + lg][wr + l15][0];
        f16x8 a1 = *(const f16x8*)&Ah[(k0 >> 3) + lg][wr + 16 + l15][0];
        const _Float16* wb = Wf_l + (k0 >> 5) * 8192 + (lg * 16 + l15) * 8;
#pragma unroll
        for (int t = 0; t < 8; ++t) {
            int tg = (wc >> 4) + t;
            f16x8 bl = *(const f16x8*)&wb[tg * 512];
            f16x8 br = *(const f16x8*)&wb[65536 + tg * 512];
            accl[0][t] = __builtin_amdgcn_mfma_f32_16x16x32_f16(a0, bl,
                                                                accl[0][t], 0, 0, 0);
            accl[1][t] = __builtin_amdgcn_mfma_f32_16x16x32_f16(a1, bl,
                                                                accl[1][t], 0, 0, 0);
            accr[0][t] = __builtin_amdgcn_mfma_f32_16x16x32_f16(a0, br,
                                                                accr[0][t], 0, 0, 0);
            accr[1][t] = __builtin_amdgcn_mfma_f32_16x16x32_f16(a1, br,
                                                                accr[1][t], 0, 0, 0);
        }
    }

    // ---- epilogue: Zl, Zr = +bias, both fp16 ----
    float bv[8];
#pragma unroll
    for (int t = 0; t < 8; ++t) bv[t] = bias[wc + t * 16 + l15];
#pragma unroll
    for (int rt = 0; rt < 2; ++rt) {
#pragma unroll
        for (int r = 0; r < 4; ++r) {
            int grow = r0 + wr + rt * 16 + lg * 4 + r;
            if (grow >= M) continue;
#pragma unroll
            for (int t = 0; t < 8; ++t) {
                int col = wc + t * 16 + l15;
                zl[(size_t)grow * 256 + col] = (_Float16)accl[rt][t][r];
                zr[(size_t)grow * 256 + col] =
                    (_Float16)(accr[rt][t][r] + bv[t]);
            }
        }
    }
}

// ------------------------------- combine ----------------------------------
// h'[v] = relu?( mean_{u in N(v)} Zl[u] + Zr[v] ). One wave/node; two lane
// halves take alternating edges, 2x unrolled (4 gathers in flight), 16B/lane.
__global__ void combine_kernel(const _Float16* __restrict__ zl,
                               const _Float16* __restrict__ zr,
                               const int* __restrict__ rowptr,
                               const int* __restrict__ csr_src,
                               const float* __restrict__ inv_deg,
                               _Float16* __restrict__ hout,
                               float* __restrict__ fout, int n, int mode) {
    int wave = threadIdx.x >> 6, lane = threadIdx.x & 63;
    int v = blockIdx.x * 4 + wave;
    if (v >= n) return;
    int half = lane >> 5, li = lane & 31;
    int beg = rowptr[v], end = rowptr[v + 1];
    float acc[8] = {0.f, 0.f, 0.f, 0.f, 0.f, 0.f, 0.f, 0.f};
    int e = beg + half;
    for (; e + 2 < end; e += 4) {
        int u0 = csr_src[e], u1 = csr_src[e + 2];
        f16x8 ta = *(const f16x8*)&zl[(size_t)u0 * 256 + li * 8];
        f16x8 tb = *(const f16x8*)&zl[(size_t)u1 * 256 + li * 8];
#pragma unroll
        for (int j = 0; j < 8; ++j) acc[j] += (float)ta[j] + (float)tb[j];
    }
    for (; e < end; e += 2) {
        int u = csr_src[e];
        f16x8 t = *(const f16x8*)&zl[(size_t)u * 256 + li * 8];
#pragma unroll
        for (int j = 0; j < 8; ++j) acc[j] += (float)t[j];
    }
#pragma unroll
    for (int j = 0; j < 8; ++j) acc[j] += __shfl_xor(acc[j], 32);
    if (half == 0) {
        float sc = inv_deg[v];
        f16x8 zp = *(const f16x8*)&zr[(size_t)v * 256 + li * 8];
        float o[8];
#pragma unroll
        for (int j = 0; j < 8; ++j) o[j] = acc[j] * sc + (float)zp[j];
        if (mode == 0) {
            f16x8 p;
#pragma unroll
            for (int j = 0; j < 8; ++j) p[j] = (_Float16)fmaxf(o[j], 0.0f);
            *(f16x8*)&hout[(size_t)v * 256 + li * 8] = p;
        } else {
            float4* op = (float4*)&fout[(size_t)v * 256 + li * 8];
            op[0] = make_float4(o[0], o[1], o[2], o[3]);
            op[1] = make_float4(o[4], o[5], o[6], o[7]);
        }
    }
}

// --------------------------------- launch ---------------------------------
extern "C" void kernel_launch(void* const* d_in, const int* in_sizes, int n_in,
                              void* d_out, int out_size, void* d_ws, size_t ws_size,
                              hipStream_t stream) {
    const int D = 256;
    const int N = in_sizes[0] / D;
    const int E = in_sizes[1] / 2;
    const int L = in_sizes[2] / (D * D);

    const float* x  = (const float*)d_in[0];
    const int*   ei = (const int*)d_in[1];
    const float* Wl = (const float*)d_in[2];
    const float* Wr = (const float*)d_in[3];
    const float* b  = (const float*)d_in[4];
    const int* src = ei;
    const int* dst = ei + E;

    size_t off = 0;
    auto alloc = [&](size_t bytes) {
        void* p = (char*)d_ws + off;
        off += (bytes + 255) & ~(size_t)255;
        return p;
    };
    int*   deg     = (int*)alloc((size_t)N * 4);
    int*   rowptr  = (int*)alloc((size_t)(N + 1) * 4);
    int*   cursor  = (int*)alloc((size_t)N * 4);
    float* inv_deg = (float*)alloc((size_t)N * 4);
    int*   csr_src = (int*)alloc((size_t)E * 4);
    int*   partial = (int*)alloc(256 * 4);
    _Float16* zl = (_Float16*)alloc((size_t)N * D * 2);
    _Float16* zr = (_Float16*)alloc((size_t)N * D * 2);
    _Float16* Wf = (_Float16*)alloc((size_t)L * 2 * 65536 * 2);
    (void)ws_size;

    // hA (fp16 hidden state) aliases d_out; final combine overwrites with fp32
    _Float16* hA = (_Float16*)d_out;
    float* outf = (float*)d_out;

    const int scan_blocks = (N + 1023) / 1024;

    // CSR build
    hipMemsetAsync(deg, 0, (size_t)N * 4, stream);
    hipLaunchKernelGGL(count_deg_kernel, dim3((E + 255) / 256), dim3(256), 0,
                       stream, dst, deg, E);
    hipLaunchKernelGGL(scan_phase1, dim3(scan_blocks), dim3(256), 0, stream,
                       deg, partial, N);
    hipLaunchKernelGGL(scan_phase2, dim3(1), dim3(256), 0, stream,
                       partial, scan_blocks, rowptr, N, E);
    hipLaunchKernelGGL(scan_phase3, dim3(scan_blocks), dim3(256), 0, stream,
                       deg, partial, rowptr, cursor, inv_deg, N);
    hipLaunchKernelGGL(fill_csr_kernel, dim3((E + 255) / 256), dim3(256), 0,
                       stream, src, dst, cursor, csr_src, E);

    // W -> fp16 fragment order
    int wtotal = L * 2 * 65536;
    hipLaunchKernelGGL(presplit_w_kernel, dim3((wtotal + 255) / 256), dim3(256),
                       0, stream, Wl, Wr, Wf, wtotal);

    const int gemm_blocks = (N + 63) / 64;
    const int comb_blocks = (N + 3) / 4;
    for (int l = 0; l < L; ++l) {
        hipLaunchKernelGGL(dual_gemm, dim3(gemm_blocks), dim3(256), 0, stream,
                           hA, x, (l == 0) ? 1 : 0, zl, zr,
                           Wf + (size_t)l * 131072, b + (size_t)l * D, N);
        hipLaunchKernelGGL(combine_kernel, dim3(comb_blocks), dim3(256), 0,
                           stream, zl, zr, rowptr, csr_src, inv_deg,
                           hA, outf, N, (l < L - 1) ? 0 : 1);
    }
}